// Round 22
// baseline (163.779 us; speedup 1.0000x reference)
//
#include <hip/hip_runtime.h>
#include <hip/hip_bf16.h>

// Problem constants (MultiHeadAttention): B=4, T=2048, C=1024, H=16, D=64
#define BB 4
#define TT 2048
#define CC 1024
#define HH 16
#define DD 64
#define MM (BB * TT)   // 8192
#define NN_QKV 3072    // 3 * 16 * 64

typedef __attribute__((ext_vector_type(8))) short short8;
typedef __attribute__((ext_vector_type(4))) short short4v;
typedef __attribute__((ext_vector_type(4))) int i32x4;
typedef __attribute__((ext_vector_type(4))) float f32x4;
typedef __attribute__((ext_vector_type(16))) float f32x16;

// HW 2^x (v_exp_f32). __exp2f doesn't exist in this toolchain's headers.
static __device__ __forceinline__ float exp2_hw(float x) {
  return __builtin_amdgcn_exp2f(x);
}

static __device__ __forceinline__ short f2bf(float f) {
  __hip_bfloat16 h = __float2bfloat16(f);
  short s;
  __builtin_memcpy(&s, &h, 2);
  return s;
}

// Fast bf16 pack for FINITE NON-NEGATIVE values (P = exp2(s)):
// round-to-nearest via +0x8000 then truncate.
static __device__ __forceinline__ unsigned int pack2rn(float a, float b) {
  unsigned int ua, ub;
  __builtin_memcpy(&ua, &a, 4);
  __builtin_memcpy(&ub, &b, 4);
  ua += 0x8000u;
  ub += 0x8000u;
  return (ua >> 16) | (ub & 0xFFFF0000u);
}

static __device__ __forceinline__ f32x16 zero16() {
  f32x16 z;
#pragma unroll
  for (int i = 0; i < 16; ++i) z[i] = 0.f;
  return z;
}

// V swizzle: two-term so staging-write banks depend on BOTH the key row and
// the d-chunk (one-term (d&7)<<4 is a 16-way write conflict).
static __device__ __forceinline__ int swzv(int d) {
  return (((d & 7) ^ ((d >> 3) & 7)) << 4);
}

// global -> LDS direct copy, 16B/lane. LDS dest wave-uniform base + lane*16.
static __device__ __forceinline__ void gld16(const void* g, void* l) {
  __builtin_amdgcn_global_load_lds(
      (const __attribute__((address_space(1))) unsigned int*)g,
      (__attribute__((address_space(3))) unsigned int*)l, 16, 0, 0);
}

// ---------------------------------------------------------------------------
// Convert f32 -> bf16, 8 elements/thread; two jobs in one launch.
// ---------------------------------------------------------------------------
__global__ __launch_bounds__(256) void cvt8x2_kernel(
    const float* __restrict__ ina, short* __restrict__ outa, int n8a,
    const float* __restrict__ inb, short* __restrict__ outb, int n8b) {
  int i = blockIdx.x * 256 + threadIdx.x;
  const float* in;
  short* out;
  if (i < n8a) {
    in = ina; out = outa;
  } else {
    i -= n8a;
    if (i >= n8b) return;
    in = inb; out = outb;
  }
  const float4 a = ((const float4*)in)[i * 2];
  const float4 b = ((const float4*)in)[i * 2 + 1];
  short8 o;
  o[0] = f2bf(a.x); o[1] = f2bf(a.y); o[2] = f2bf(a.z); o[3] = f2bf(a.w);
  o[4] = f2bf(b.x); o[5] = f2bf(b.y); o[6] = f2bf(b.z); o[7] = f2bf(b.w);
  ((short8*)out)[i] = o;
}

// ---------------------------------------------------------------------------
// Transpose-convert W[h][c][d] f32 -> Wt[(sel*16+h)*64+d][c] bf16.
// ---------------------------------------------------------------------------
__global__ __launch_bounds__(256) void cvtw_kernel(
    const float* __restrict__ Wq, const float* __restrict__ Wk,
    const float* __restrict__ Wv, short* __restrict__ Wt) {
  __shared__ float tile[64][65];
  const int tid = threadIdx.x;
  const int h = blockIdx.x;
  const int c0 = blockIdx.y * 64;
  const int sel = blockIdx.z;
  const float* W = (sel == 0) ? Wq : (sel == 1) ? Wk : Wv;

#pragma unroll
  for (int it = 0; it < 16; ++it) {
    int e = it * 256 + tid;
    int cc = e >> 6, d = e & 63;
    tile[d][cc] = W[((size_t)h * CC + c0 + cc) * DD + d];
  }
  __syncthreads();
#pragma unroll
  for (int it = 0; it < 16; ++it) {
    int e = it * 256 + tid;
    int d = e >> 6, cc = e & 63;
    Wt[((size_t)((sel * 16 + h) * 64 + d)) * CC + c0 + cc] = f2bf(tile[d][cc]);
  }
}

// ---------------------------------------------------------------------------
// GEMM on 32x32x16 MFMA (r17/r18-validated skeleton): 128x128 tile, BK=64,
// 4 waves (2x2), each wave 64x64 = 2x2 of 32x32 frags. 2-barrier loop,
// XOR-swizzled staging (0 bank conflicts measured).
// MODE 0: qkv epilogue -> bf16 scatter to q/k/v, q scaled 0.125*log2e.
// MODE 1: proj epilogue -> f32 out + bias.
// C layout (HW-verified): col = lane&31, row = (r&3)+8*(r>>2)+4*(lane>>5).
// ---------------------------------------------------------------------------
template <int MODE>
__global__ __launch_bounds__(256) void gemm32_kernel(
    const short* __restrict__ A, const short* __restrict__ Bt,
    const float* __restrict__ bias,
    __hip_bfloat16* __restrict__ Oq, __hip_bfloat16* __restrict__ Ok,
    __hip_bfloat16* __restrict__ Ov, float* __restrict__ Of) {
  __shared__ __align__(16) char Als[128 * 128];  // [row][slot*16B], 16 KB
  __shared__ __align__(16) char Bls[128 * 128];

  const int tid = threadIdx.x;
  const int w = tid >> 6, l = tid & 63;
  const int l31 = l & 31, hi = l >> 5;
  const int wr = w >> 1, wc = w & 1;
  const int m0 = blockIdx.x * 128;
  const int n0 = blockIdx.y * 128;

  const int srow = tid >> 3;            // 0..31 within issue
  const int schunk = tid & 7;
  const int sswz = (schunk ^ (srow & 7)) * 8;  // pre-swizzled 16B chunk offset

  f32x16 acc[2][2];
  acc[0][0] = zero16(); acc[0][1] = zero16();
  acc[1][0] = zero16(); acc[1][1] = zero16();

#pragma unroll 1
  for (int kt = 0; kt < CC; kt += 64) {
    __syncthreads();
#pragma unroll
    for (int i = 0; i < 4; ++i) {
      gld16(A + (size_t)(m0 + i * 32 + srow) * CC + kt + sswz,
            Als + i * 4096 + w * 1024);
      gld16(Bt + (size_t)(n0 + i * 32 + srow) * CC + kt + sswz,
            Bls + i * 4096 + w * 1024);
    }
    __syncthreads();

#pragma unroll
    for (int ks = 0; ks < 4; ++ks) {
      const int c = ks * 2 + hi;
      short8 af[2], bf[2];
#pragma unroll
      for (int mi = 0; mi < 2; ++mi) {
        const int row = wr * 64 + mi * 32 + l31;
        af[mi] = *(const short8*)(Als + row * 128 + ((c ^ (row & 7)) * 16));
      }
#pragma unroll
      for (int ni = 0; ni < 2; ++ni) {
        const int row = wc * 64 + ni * 32 + l31;
        bf[ni] = *(const short8*)(Bls + row * 128 + ((c ^ (row & 7)) * 16));
      }
      __builtin_amdgcn_s_setprio(1);
#pragma unroll
      for (int mi = 0; mi < 2; ++mi)
#pragma unroll
        for (int ni = 0; ni < 2; ++ni)
          acc[mi][ni] = __builtin_amdgcn_mfma_f32_32x32x16_bf16(
              af[mi], bf[ni], acc[mi][ni], 0, 0, 0);
      __builtin_amdgcn_s_setprio(0);
    }
  }

  if (MODE == 0) {
    const int b = m0 >> 11;
#pragma unroll
    for (int ni = 0; ni < 2; ++ni) {
      const int nbase = n0 + wc * 64 + ni * 32;
      const int sel = nbase >> 10;
      const int h = (nbase >> 6) & 15;
      const int d = (nbase & 63) + l31;
      __hip_bfloat16* O = (sel == 0) ? Oq : (sel == 1) ? Ok : Ov;
      // q scale: 1/sqrt(64) * log2(e)  (softmax done in exp2 domain)
      const float sc = (sel == 0) ? 0.18033688011112042f : 1.0f;
#pragma unroll
      for (int mi = 0; mi < 2; ++mi) {
#pragma unroll
        for (int r = 0; r < 16; ++r) {
          const int m = m0 + wr * 64 + mi * 32 + (r & 3) + 8 * (r >> 2) + 4 * hi;
          const int t = m & (TT - 1);
          O[(((size_t)b * HH + h) * TT + t) * DD + d] =
              __float2bfloat16(acc[mi][ni][r] * sc);
        }
      }
    }
  } else {
#pragma unroll
    for (int ni = 0; ni < 2; ++ni) {
      const int n = n0 + wc * 64 + ni * 32 + l31;
      const float bv = bias[n];
#pragma unroll
      for (int mi = 0; mi < 2; ++mi) {
#pragma unroll
        for (int r = 0; r < 16; ++r) {
          const int m = m0 + wr * 64 + mi * 32 + (r & 3) + 8 * (r >> 2) + 4 * hi;
          Of[(size_t)m * CC + n] = acc[mi][ni][r] + bv;
        }
      }
    }
  }
}

// ---------------------------------------------------------------------------
// MFMA flash attention, 32x32 swapped-operand, intra-block split-K
// (r18/r20-validated body). Round 22: placement-robust qt map via a 4x4
// magic square — qt = magic[flat&3][(flat>>8)&3], hb = (flat>>2)&63.
// Rows AND columns sum to 30, so both plausible block->CU co-residency
// patterns (consecutive quadruple = column; stride-256 quadruple = row)
// are balanced at 34 pair-units/CU; map is bijective (bit partition).
// ---------------------------------------------------------------------------
__global__ __launch_bounds__(512) void attn32_kernel(
    const __hip_bfloat16* __restrict__ qg, const __hip_bfloat16* __restrict__ kg,
    const __hip_bfloat16* __restrict__ vg, __hip_bfloat16* __restrict__ att) {
  __shared__ __align__(16) char LDS[34816];
  char* Ks = LDS;
  char* Vt0 = LDS + 16384;
  char* Vt1 = LDS + 24576;

  const int tid = threadIdx.x;
  const int w = tid >> 6, l = tid & 63;
  const int l31 = l & 31, hi = l >> 5;
  const int w4 = w & 3, g = w >> 2;

  const int flat = blockIdx.x;
  // Durer magic square minus 1: rows & cols sum 30, values 0..15 distinct.
  const int mg[16] = {15, 2, 1, 12, 4, 9, 10, 7, 8, 5, 6, 11, 3, 14, 13, 0};
  const int qt = mg[(flat & 3) * 4 + ((flat >> 8) & 3)];
  const int hb = (flat >> 2) & 63;
  const int h = hb & 15, b = hb >> 4;
  const size_t base = ((size_t)b * HH + h) * TT * DD;

  const int q0w = qt * 128 + w4 * 32;
  const int myq = q0w + l31;

  const short* Kg = (const short*)kg + base;
  const short* Vg = (const short*)vg + base;
  const int kr = tid >> 3;
  const int kc = tid & 7;
  const int vs = tid >> 3;
  const int vd0 = (tid & 7) * 8;

  const short* Qp = (const short*)qg + base + (size_t)myq * DD;
  const short8 qf0 = *(const short8*)(Qp + 0 + hi * 8);
  const short8 qf1 = *(const short8*)(Qp + 16 + hi * 8);
  const short8 qf2 = *(const short8*)(Qp + 32 + hi * 8);
  const short8 qf3 = *(const short8*)(Qp + 48 + hi * 8);

  f32x16 o0 = zero16(), o1 = zero16();
  float lsum = 0.f;

  const int npair = qt + 1;

#pragma unroll 1
  for (int pt = 0; pt < npair; ++pt) {
    const int sb = pt * 128;

    gld16(Kg + (size_t)(sb + kr) * DD + ((kc ^ (kr & 7)) * 8), Ks + w * 1024);
    gld16(Kg + (size_t)(sb + kr + 64) * DD + ((kc ^ (kr & 7)) * 8),
          Ks + 8192 + w * 1024);
    const short8 va = *(const short8*)(Vg + (size_t)(sb + vs) * DD + vd0);
    const short8 vb = *(const short8*)(Vg + (size_t)(sb + 64 + vs) * DD + vd0);
#pragma unroll
    for (int e = 0; e < 8; ++e) {
      const int d = vd0 + e;
      *(short*)(Vt0 + d * 128 + ((vs * 2) ^ swzv(d))) = va[e];
      *(short*)(Vt1 + d * 128 + ((vs * 2) ^ swzv(d))) = vb[e];
    }
    __syncthreads();

    const int sbg = sb + g * 64;
    const char* Vtg = g ? Vt1 : Vt0;
#pragma unroll
    for (int ks = 0; ks < 2; ++ks) {
      const int sbh = sbg + ks * 32;
      if (sbh > q0w + 31) continue;

      const int krow = g * 64 + ks * 32 + l31;
      const char* Kr = Ks + krow * 128;
      const int rsz = (krow & 7) << 4;
      const short8 kf0 = *(const short8*)(Kr + ((0 * 32 + hi * 16) ^ rsz));
      const short8 kf1 = *(const short8*)(Kr + ((1 * 32 + hi * 16) ^ rsz));
      const short8 kf2 = *(const short8*)(Kr + ((2 * 32 + hi * 16) ^ rsz));
      const short8 kf3 = *(const short8*)(Kr + ((3 * 32 + hi * 16) ^ rsz));
      f32x16 sT = zero16();
      __builtin_amdgcn_s_setprio(1);
      sT = __builtin_amdgcn_mfma_f32_32x32x16_bf16(kf0, qf0, sT, 0, 0, 0);
      sT = __builtin_amdgcn_mfma_f32_32x32x16_bf16(kf1, qf1, sT, 0, 0, 0);
      sT = __builtin_amdgcn_mfma_f32_32x32x16_bf16(kf2, qf2, sT, 0, 0, 0);
      sT = __builtin_amdgcn_mfma_f32_32x32x16_bf16(kf3, qf3, sT, 0, 0, 0);
      __builtin_amdgcn_s_setprio(0);

      float p[16];
      if (sbh == q0w) {
#pragma unroll
        for (int r = 0; r < 16; ++r) {
          const int sg = sbh + (r & 3) + 8 * (r >> 2) + 4 * hi;
          p[r] = (sg > myq) ? -INFINITY : sT[r];
        }
      } else {
#pragma unroll
        for (int r = 0; r < 16; ++r) p[r] = sT[r];
      }

      float ps = 0.f;
#pragma unroll
      for (int r = 0; r < 16; ++r) {
        p[r] = exp2_hw(p[r]);
        ps += p[r];
      }
      lsum += ps;

      unsigned int W[4][2], X[4][2];
#pragma unroll
      for (int qd = 0; qd < 4; ++qd) {
        W[qd][0] = pack2rn(p[4 * qd + 0], p[4 * qd + 1]);
        W[qd][1] = pack2rn(p[4 * qd + 2], p[4 * qd + 3]);
        X[qd][0] = __shfl_xor((int)W[qd][0], 32);
        X[qd][1] = __shfl_xor((int)W[qd][1], 32);
      }

#pragma unroll
      for (int kst = 0; kst < 2; ++kst) {
        union { i32x4 i; short8 s; } A;
        A.i[0] = hi ? (int)X[2 * kst + 1][0] : (int)W[2 * kst][0];
        A.i[1] = hi ? (int)X[2 * kst + 1][1] : (int)W[2 * kst][1];
        A.i[2] = hi ? (int)W[2 * kst + 1][0] : (int)X[2 * kst][0];
        A.i[3] = hi ? (int)W[2 * kst + 1][1] : (int)X[2 * kst][1];
        const int kb = (ks * 32 + kst * 16 + hi * 8) * 2;
        const int r0 = l31, r1 = 32 + l31;
        const short8 vf0 = *(const short8*)(Vtg + r0 * 128 + (kb ^ swzv(r0)));
        const short8 vf1 = *(const short8*)(Vtg + r1 * 128 + (kb ^ swzv(r1)));
        __builtin_amdgcn_s_setprio(1);
        o0 = __builtin_amdgcn_mfma_f32_32x32x16_bf16(vf0, A.s, o0, 0, 0, 0);
        o1 = __builtin_amdgcn_mfma_f32_32x32x16_bf16(vf1, A.s, o1, 0, 0, 0);
        __builtin_amdgcn_s_setprio(0);
      }
    }
    __syncthreads();
  }

  lsum += __shfl_xor(lsum, 32);

  // ---- split-K combine, single pass: g==1 publishes o0|o1|lsum (33 floats
  // per thread, stride 33, 33.8KB <= 34.8KB LDS), g==0 accumulates + stores.
  float* comb = (float*)LDS;
  const int idx = (w4 * 64 + l) * 33;
  if (g == 1) {
#pragma unroll
    for (int i = 0; i < 16; ++i) {
      comb[idx + i] = o0[i];
      comb[idx + 16 + i] = o1[i];
    }
    comb[idx + 32] = lsum;
  }
  __syncthreads();
  if (g == 0) {
#pragma unroll
    for (int i = 0; i < 16; ++i) {
      o0[i] += comb[idx + i];
      o1[i] += comb[idx + 16 + i];
    }
    lsum += comb[idx + 32];

    const float inv = 1.0f / lsum;
    short* orow = (short*)att + ((size_t)b * TT + myq) * CC + h * DD;
#pragma unroll
    for (int j = 0; j < 4; ++j) {
      short4v s0, s1;
#pragma unroll
      for (int i = 0; i < 4; ++i) {
        s0[i] = f2bf(o0[4 * j + i] * inv);
        s1[i] = f2bf(o1[4 * j + i] * inv);
      }
      *(short4v*)(orow + 8 * j + 4 * hi) = s0;
      *(short4v*)(orow + 32 + 8 * j + 4 * hi) = s1;
    }
  }
}

// ---------------------------------------------------------------------------
extern "C" void kernel_launch(void* const* d_in, const int* in_sizes, int n_in,
                              void* d_out, int out_size, void* d_ws, size_t ws_size,
                              hipStream_t stream) {
  const float* x  = (const float*)d_in[0];
  const float* Wk = (const float*)d_in[1];
  const float* Wq = (const float*)d_in[2];
  const float* Wv = (const float*)d_in[3];
  const float* pw = (const float*)d_in[4];
  const float* pb = (const float*)d_in[5];
  float* out = (float*)d_out;

  const size_t QE = (size_t)BB * HH * TT * DD;
  // ws layout (bf16 elems): q | k | v | xbf/att (aliased) | Wt | pwbf
  // pwbf gets its OWN region (r21 bug: pwbf aliased Wt, but cvt8x2 now runs
  // before cvtw, which would clobber it). Total ~72.3 MB.
  __hip_bfloat16* q   = (__hip_bfloat16*)d_ws;
  __hip_bfloat16* k   = q + QE;
  __hip_bfloat16* v   = k + QE;
  short* xbf          = (short*)(v + QE);
  __hip_bfloat16* att = (__hip_bfloat16*)xbf;   // aliased: xbf dead after qkv GEMM
  short* Wt           = xbf + QE;               // [3072][1024] bf16
  short* pwbf         = Wt + (size_t)NN_QKV * CC;  // [1024][1024] bf16

  const int n8x = MM * CC / 8;      // 1,048,576
  const int n8p = CC * CC / 8;      // 131,072
  cvt8x2_kernel<<<(n8x + n8p + 255) / 256, 256, 0, stream>>>(
      x, xbf, n8x, pw, pwbf, n8p);
  cvtw_kernel<<<dim3(HH, CC / 64, 3), 256, 0, stream>>>(Wq, Wk, Wv, Wt);
  gemm32_kernel<0><<<dim3(MM / 128, NN_QKV / 128), 256, 0, stream>>>(
      xbf, Wt, nullptr, q, k, v, nullptr);
  attn32_kernel<<<dim3(1024, 1, 1), 512, 0, stream>>>(q, k, v, att);
  gemm32_kernel<1><<<dim3(MM / 128, CC / 128), 256, 0, stream>>>(
      (const short*)att, pwbf, pb, nullptr, nullptr, nullptr, out);
}

// Round 23
// 156.834 us; speedup vs baseline: 1.0443x; 1.0443x over previous
//
#include <hip/hip_runtime.h>
#include <hip/hip_bf16.h>

// Problem constants (MultiHeadAttention): B=4, T=2048, C=1024, H=16, D=64
#define BB 4
#define TT 2048
#define CC 1024
#define HH 16
#define DD 64
#define MM (BB * TT)   // 8192
#define NN_QKV 3072    // 3 * 16 * 64

typedef __attribute__((ext_vector_type(8))) short short8;
typedef __attribute__((ext_vector_type(4))) short short4v;
typedef __attribute__((ext_vector_type(4))) int i32x4;
typedef __attribute__((ext_vector_type(4))) float f32x4;
typedef __attribute__((ext_vector_type(16))) float f32x16;

// HW 2^x (v_exp_f32). __exp2f doesn't exist in this toolchain's headers.
static __device__ __forceinline__ float exp2_hw(float x) {
  return __builtin_amdgcn_exp2f(x);
}

static __device__ __forceinline__ short f2bf(float f) {
  __hip_bfloat16 h = __float2bfloat16(f);
  short s;
  __builtin_memcpy(&s, &h, 2);
  return s;
}

// Fast bf16 pack for FINITE NON-NEGATIVE values (P = exp2(s)):
// round-to-nearest via +0x8000 then truncate.
static __device__ __forceinline__ unsigned int pack2rn(float a, float b) {
  unsigned int ua, ub;
  __builtin_memcpy(&ua, &a, 4);
  __builtin_memcpy(&ub, &b, 4);
  ua += 0x8000u;
  ub += 0x8000u;
  return (ua >> 16) | (ub & 0xFFFF0000u);
}

static __device__ __forceinline__ f32x16 zero16() {
  f32x16 z;
#pragma unroll
  for (int i = 0; i < 16; ++i) z[i] = 0.f;
  return z;
}

// V swizzle: two-term so staging-write banks depend on BOTH the key row and
// the d-chunk (one-term (d&7)<<4 is a 16-way write conflict).
static __device__ __forceinline__ int swzv(int d) {
  return (((d & 7) ^ ((d >> 3) & 7)) << 4);
}

// global -> LDS direct copy, 16B/lane. LDS dest wave-uniform base + lane*16.
static __device__ __forceinline__ void gld16(const void* g, void* l) {
  __builtin_amdgcn_global_load_lds(
      (const __attribute__((address_space(1))) unsigned int*)g,
      (__attribute__((address_space(3))) unsigned int*)l, 16, 0, 0);
}

// ---------------------------------------------------------------------------
// Convert f32 -> bf16, 8 elements/thread; two jobs in one launch.
// ---------------------------------------------------------------------------
__global__ __launch_bounds__(256) void cvt8x2_kernel(
    const float* __restrict__ ina, short* __restrict__ outa, int n8a,
    const float* __restrict__ inb, short* __restrict__ outb, int n8b) {
  int i = blockIdx.x * 256 + threadIdx.x;
  const float* in;
  short* out;
  if (i < n8a) {
    in = ina; out = outa;
  } else {
    i -= n8a;
    if (i >= n8b) return;
    in = inb; out = outb;
  }
  const float4 a = ((const float4*)in)[i * 2];
  const float4 b = ((const float4*)in)[i * 2 + 1];
  short8 o;
  o[0] = f2bf(a.x); o[1] = f2bf(a.y); o[2] = f2bf(a.z); o[3] = f2bf(a.w);
  o[4] = f2bf(b.x); o[5] = f2bf(b.y); o[6] = f2bf(b.z); o[7] = f2bf(b.w);
  ((short8*)out)[i] = o;
}

// ---------------------------------------------------------------------------
// Transpose-convert W[h][c][d] f32 -> Wt[(sel*16+h)*64+d][c] bf16.
// ---------------------------------------------------------------------------
__global__ __launch_bounds__(256) void cvtw_kernel(
    const float* __restrict__ Wq, const float* __restrict__ Wk,
    const float* __restrict__ Wv, short* __restrict__ Wt) {
  __shared__ float tile[64][65];
  const int tid = threadIdx.x;
  const int h = blockIdx.x;
  const int c0 = blockIdx.y * 64;
  const int sel = blockIdx.z;
  const float* W = (sel == 0) ? Wq : (sel == 1) ? Wk : Wv;

#pragma unroll
  for (int it = 0; it < 16; ++it) {
    int e = it * 256 + tid;
    int cc = e >> 6, d = e & 63;
    tile[d][cc] = W[((size_t)h * CC + c0 + cc) * DD + d];
  }
  __syncthreads();
#pragma unroll
  for (int it = 0; it < 16; ++it) {
    int e = it * 256 + tid;
    int d = e >> 6, cc = e & 63;
    Wt[((size_t)((sel * 16 + h) * 64 + d)) * CC + c0 + cc] = f2bf(tile[d][cc]);
  }
}

// ---------------------------------------------------------------------------
// GEMM on 32x32x16 MFMA (r17/r18-validated skeleton): 128x128 tile, BK=64,
// 4 waves (2x2), each wave 64x64 = 2x2 of 32x32 frags. 2-barrier loop,
// XOR-swizzled staging (0 bank conflicts measured).
// MODE 0: qkv epilogue -> bf16 scatter to q/k/v, q scaled 0.125*log2e.
// MODE 1: proj epilogue -> f32 out + bias.
// C layout (HW-verified): col = lane&31, row = (r&3)+8*(r>>2)+4*(lane>>5).
// ---------------------------------------------------------------------------
template <int MODE>
__global__ __launch_bounds__(256) void gemm32_kernel(
    const short* __restrict__ A, const short* __restrict__ Bt,
    const float* __restrict__ bias,
    __hip_bfloat16* __restrict__ Oq, __hip_bfloat16* __restrict__ Ok,
    __hip_bfloat16* __restrict__ Ov, float* __restrict__ Of) {
  __shared__ __align__(16) char Als[128 * 128];  // [row][slot*16B], 16 KB
  __shared__ __align__(16) char Bls[128 * 128];

  const int tid = threadIdx.x;
  const int w = tid >> 6, l = tid & 63;
  const int l31 = l & 31, hi = l >> 5;
  const int wr = w >> 1, wc = w & 1;
  const int m0 = blockIdx.x * 128;
  const int n0 = blockIdx.y * 128;

  const int srow = tid >> 3;            // 0..31 within issue
  const int schunk = tid & 7;
  const int sswz = (schunk ^ (srow & 7)) * 8;  // pre-swizzled 16B chunk offset

  f32x16 acc[2][2];
  acc[0][0] = zero16(); acc[0][1] = zero16();
  acc[1][0] = zero16(); acc[1][1] = zero16();

#pragma unroll 1
  for (int kt = 0; kt < CC; kt += 64) {
    __syncthreads();
#pragma unroll
    for (int i = 0; i < 4; ++i) {
      gld16(A + (size_t)(m0 + i * 32 + srow) * CC + kt + sswz,
            Als + i * 4096 + w * 1024);
      gld16(Bt + (size_t)(n0 + i * 32 + srow) * CC + kt + sswz,
            Bls + i * 4096 + w * 1024);
    }
    __syncthreads();

#pragma unroll
    for (int ks = 0; ks < 4; ++ks) {
      const int c = ks * 2 + hi;
      short8 af[2], bf[2];
#pragma unroll
      for (int mi = 0; mi < 2; ++mi) {
        const int row = wr * 64 + mi * 32 + l31;
        af[mi] = *(const short8*)(Als + row * 128 + ((c ^ (row & 7)) * 16));
      }
#pragma unroll
      for (int ni = 0; ni < 2; ++ni) {
        const int row = wc * 64 + ni * 32 + l31;
        bf[ni] = *(const short8*)(Bls + row * 128 + ((c ^ (row & 7)) * 16));
      }
      __builtin_amdgcn_s_setprio(1);
#pragma unroll
      for (int mi = 0; mi < 2; ++mi)
#pragma unroll
        for (int ni = 0; ni < 2; ++ni)
          acc[mi][ni] = __builtin_amdgcn_mfma_f32_32x32x16_bf16(
              af[mi], bf[ni], acc[mi][ni], 0, 0, 0);
      __builtin_amdgcn_s_setprio(0);
    }
  }

  if (MODE == 0) {
    const int b = m0 >> 11;
#pragma unroll
    for (int ni = 0; ni < 2; ++ni) {
      const int nbase = n0 + wc * 64 + ni * 32;
      const int sel = nbase >> 10;
      const int h = (nbase >> 6) & 15;
      const int d = (nbase & 63) + l31;
      __hip_bfloat16* O = (sel == 0) ? Oq : (sel == 1) ? Ok : Ov;
      // q scale: 1/sqrt(64) * log2(e)  (softmax done in exp2 domain)
      const float sc = (sel == 0) ? 0.18033688011112042f : 1.0f;
#pragma unroll
      for (int mi = 0; mi < 2; ++mi) {
#pragma unroll
        for (int r = 0; r < 16; ++r) {
          const int m = m0 + wr * 64 + mi * 32 + (r & 3) + 8 * (r >> 2) + 4 * hi;
          const int t = m & (TT - 1);
          O[(((size_t)b * HH + h) * TT + t) * DD + d] =
              __float2bfloat16(acc[mi][ni][r] * sc);
        }
      }
    }
  } else {
#pragma unroll
    for (int ni = 0; ni < 2; ++ni) {
      const int n = n0 + wc * 64 + ni * 32 + l31;
      const float bv = bias[n];
#pragma unroll
      for (int mi = 0; mi < 2; ++mi) {
#pragma unroll
        for (int r = 0; r < 16; ++r) {
          const int m = m0 + wr * 64 + mi * 32 + (r & 3) + 8 * (r >> 2) + 4 * hi;
          Of[(size_t)m * CC + n] = acc[mi][ni][r] + bv;
        }
      }
    }
  }
}

// ---------------------------------------------------------------------------
// MFMA flash attention, 32x32 swapped-operand, intra-block split-K —
// r20-validated decode restored: qt from r_=flat>>6 quadruple-balanced map,
// hb = flat&63 (each dispatch round sweeps all (b,h) once -> K/V L2 reuse;
// r22's magic-square decode quadrupled FETCH_SIZE and regressed).
// ---------------------------------------------------------------------------
__global__ __launch_bounds__(512) void attn32_kernel(
    const __hip_bfloat16* __restrict__ qg, const __hip_bfloat16* __restrict__ kg,
    const __hip_bfloat16* __restrict__ vg, __hip_bfloat16* __restrict__ att) {
  __shared__ __align__(16) char LDS[34816];
  char* Ks = LDS;
  char* Vt0 = LDS + 16384;
  char* Vt1 = LDS + 24576;

  const int tid = threadIdx.x;
  const int w = tid >> 6, l = tid & 63;
  const int l31 = l & 31, hi = l >> 5;
  const int w4 = w & 3, g = w >> 2;

  const int flat = blockIdx.x;
  const int r_ = flat >> 6;
  const int qt = (r_ < 4) ? (15 - r_) : (r_ < 8) ? (r_ + 4)
               : (r_ < 12) ? (15 - r_) : (r_ - 12);
  const int hb = flat & 63;
  const int h = hb & 15, b = hb >> 4;
  const size_t base = ((size_t)b * HH + h) * TT * DD;

  const int q0w = qt * 128 + w4 * 32;
  const int myq = q0w + l31;

  const short* Kg = (const short*)kg + base;
  const short* Vg = (const short*)vg + base;
  const int kr = tid >> 3;
  const int kc = tid & 7;
  const int vs = tid >> 3;
  const int vd0 = (tid & 7) * 8;

  const short* Qp = (const short*)qg + base + (size_t)myq * DD;
  const short8 qf0 = *(const short8*)(Qp + 0 + hi * 8);
  const short8 qf1 = *(const short8*)(Qp + 16 + hi * 8);
  const short8 qf2 = *(const short8*)(Qp + 32 + hi * 8);
  const short8 qf3 = *(const short8*)(Qp + 48 + hi * 8);

  f32x16 o0 = zero16(), o1 = zero16();
  float lsum = 0.f;

  const int npair = qt + 1;

#pragma unroll 1
  for (int pt = 0; pt < npair; ++pt) {
    const int sb = pt * 128;

    gld16(Kg + (size_t)(sb + kr) * DD + ((kc ^ (kr & 7)) * 8), Ks + w * 1024);
    gld16(Kg + (size_t)(sb + kr + 64) * DD + ((kc ^ (kr & 7)) * 8),
          Ks + 8192 + w * 1024);
    const short8 va = *(const short8*)(Vg + (size_t)(sb + vs) * DD + vd0);
    const short8 vb = *(const short8*)(Vg + (size_t)(sb + 64 + vs) * DD + vd0);
#pragma unroll
    for (int e = 0; e < 8; ++e) {
      const int d = vd0 + e;
      *(short*)(Vt0 + d * 128 + ((vs * 2) ^ swzv(d))) = va[e];
      *(short*)(Vt1 + d * 128 + ((vs * 2) ^ swzv(d))) = vb[e];
    }
    __syncthreads();

    const int sbg = sb + g * 64;
    const char* Vtg = g ? Vt1 : Vt0;
#pragma unroll
    for (int ks = 0; ks < 2; ++ks) {
      const int sbh = sbg + ks * 32;
      if (sbh > q0w + 31) continue;

      const int krow = g * 64 + ks * 32 + l31;
      const char* Kr = Ks + krow * 128;
      const int rsz = (krow & 7) << 4;
      const short8 kf0 = *(const short8*)(Kr + ((0 * 32 + hi * 16) ^ rsz));
      const short8 kf1 = *(const short8*)(Kr + ((1 * 32 + hi * 16) ^ rsz));
      const short8 kf2 = *(const short8*)(Kr + ((2 * 32 + hi * 16) ^ rsz));
      const short8 kf3 = *(const short8*)(Kr + ((3 * 32 + hi * 16) ^ rsz));
      f32x16 sT = zero16();
      __builtin_amdgcn_s_setprio(1);
      sT = __builtin_amdgcn_mfma_f32_32x32x16_bf16(kf0, qf0, sT, 0, 0, 0);
      sT = __builtin_amdgcn_mfma_f32_32x32x16_bf16(kf1, qf1, sT, 0, 0, 0);
      sT = __builtin_amdgcn_mfma_f32_32x32x16_bf16(kf2, qf2, sT, 0, 0, 0);
      sT = __builtin_amdgcn_mfma_f32_32x32x16_bf16(kf3, qf3, sT, 0, 0, 0);
      __builtin_amdgcn_s_setprio(0);

      float p[16];
      if (sbh == q0w) {
#pragma unroll
        for (int r = 0; r < 16; ++r) {
          const int sg = sbh + (r & 3) + 8 * (r >> 2) + 4 * hi;
          p[r] = (sg > myq) ? -INFINITY : sT[r];
        }
      } else {
#pragma unroll
        for (int r = 0; r < 16; ++r) p[r] = sT[r];
      }

      float ps = 0.f;
#pragma unroll
      for (int r = 0; r < 16; ++r) {
        p[r] = exp2_hw(p[r]);
        ps += p[r];
      }
      lsum += ps;

      unsigned int W[4][2], X[4][2];
#pragma unroll
      for (int qd = 0; qd < 4; ++qd) {
        W[qd][0] = pack2rn(p[4 * qd + 0], p[4 * qd + 1]);
        W[qd][1] = pack2rn(p[4 * qd + 2], p[4 * qd + 3]);
        X[qd][0] = __shfl_xor((int)W[qd][0], 32);
        X[qd][1] = __shfl_xor((int)W[qd][1], 32);
      }

#pragma unroll
      for (int kst = 0; kst < 2; ++kst) {
        union { i32x4 i; short8 s; } A;
        A.i[0] = hi ? (int)X[2 * kst + 1][0] : (int)W[2 * kst][0];
        A.i[1] = hi ? (int)X[2 * kst + 1][1] : (int)W[2 * kst][1];
        A.i[2] = hi ? (int)W[2 * kst + 1][0] : (int)X[2 * kst][0];
        A.i[3] = hi ? (int)W[2 * kst + 1][1] : (int)X[2 * kst][1];
        const int kb = (ks * 32 + kst * 16 + hi * 8) * 2;
        const int r0 = l31, r1 = 32 + l31;
        const short8 vf0 = *(const short8*)(Vtg + r0 * 128 + (kb ^ swzv(r0)));
        const short8 vf1 = *(const short8*)(Vtg + r1 * 128 + (kb ^ swzv(r1)));
        __builtin_amdgcn_s_setprio(1);
        o0 = __builtin_amdgcn_mfma_f32_32x32x16_bf16(vf0, A.s, o0, 0, 0, 0);
        o1 = __builtin_amdgcn_mfma_f32_32x32x16_bf16(vf1, A.s, o1, 0, 0, 0);
        __builtin_amdgcn_s_setprio(0);
      }
    }
    __syncthreads();
  }

  lsum += __shfl_xor(lsum, 32);

  // ---- split-K combine, single pass: g==1 publishes o0|o1|lsum (33 floats
  // per thread, stride 33, 33.8KB <= 34.8KB LDS), g==0 accumulates + stores.
  float* comb = (float*)LDS;
  const int idx = (w4 * 64 + l) * 33;
  if (g == 1) {
#pragma unroll
    for (int i = 0; i < 16; ++i) {
      comb[idx + i] = o0[i];
      comb[idx + 16 + i] = o1[i];
    }
    comb[idx + 32] = lsum;
  }
  __syncthreads();
  if (g == 0) {
#pragma unroll
    for (int i = 0; i < 16; ++i) {
      o0[i] += comb[idx + i];
      o1[i] += comb[idx + 16 + i];
    }
    lsum += comb[idx + 32];

    const float inv = 1.0f / lsum;
    short* orow = (short*)att + ((size_t)b * TT + myq) * CC + h * DD;
#pragma unroll
    for (int j = 0; j < 4; ++j) {
      short4v s0, s1;
#pragma unroll
      for (int i = 0; i < 4; ++i) {
        s0[i] = f2bf(o0[4 * j + i] * inv);
        s1[i] = f2bf(o1[4 * j + i] * inv);
      }
      *(short4v*)(orow + 8 * j + 4 * hi) = s0;
      *(short4v*)(orow + 32 + 8 * j + 4 * hi) = s1;
    }
  }
}

// ---------------------------------------------------------------------------
extern "C" void kernel_launch(void* const* d_in, const int* in_sizes, int n_in,
                              void* d_out, int out_size, void* d_ws, size_t ws_size,
                              hipStream_t stream) {
  const float* x  = (const float*)d_in[0];
  const float* Wk = (const float*)d_in[1];
  const float* Wq = (const float*)d_in[2];
  const float* Wv = (const float*)d_in[3];
  const float* pw = (const float*)d_in[4];
  const float* pb = (const float*)d_in[5];
  float* out = (float*)d_out;

  const size_t QE = (size_t)BB * HH * TT * DD;
  // ws layout (bf16 elems): q | k | v | xbf/att (aliased) | Wt | pwbf
  // pwbf has its OWN region (cvt8x2 runs before cvtw). Total ~72.3 MB.
  __hip_bfloat16* q   = (__hip_bfloat16*)d_ws;
  __hip_bfloat16* k   = q + QE;
  __hip_bfloat16* v   = k + QE;
  short* xbf          = (short*)(v + QE);
  __hip_bfloat16* att = (__hip_bfloat16*)xbf;   // aliased: xbf dead after qkv GEMM
  short* Wt           = xbf + QE;               // [3072][1024] bf16
  short* pwbf         = Wt + (size_t)NN_QKV * CC;  // [1024][1024] bf16

  const int n8x = MM * CC / 8;      // 1,048,576
  const int n8p = CC * CC / 8;      // 131,072
  cvt8x2_kernel<<<(n8x + n8p + 255) / 256, 256, 0, stream>>>(
      x, xbf, n8x, pw, pwbf, n8p);
  cvtw_kernel<<<dim3(HH, CC / 64, 3), 256, 0, stream>>>(Wq, Wk, Wv, Wt);
  gemm32_kernel<0><<<dim3(MM / 128, NN_QKV / 128), 256, 0, stream>>>(
      xbf, Wt, nullptr, q, k, v, nullptr);
  attn32_kernel<<<dim3(1024, 1, 1), 512, 0, stream>>>(q, k, v, att);
  gemm32_kernel<1><<<dim3(MM / 128, CC / 128), 256, 0, stream>>>(
      (const short*)att, pwbf, pb, nullptr, nullptr, nullptr, out);
}